// Round 1
// baseline (163.214 us; speedup 1.0000x reference)
//
#include <hip/hip_runtime.h>
#include <hip/hip_bf16.h>
#include <math.h>

// ---------------------------------------------------------------------------
// TernaryLeNet5 forward.
// R15: RESUBMIT of R12-exact (best verified: 161.2us prior session). Round-0
// bench failed with "MI355X container failed twice" (infra, no counters) —
// no evidence to justify any edit. Re-running to establish in-session
// baseline + rocprof counters.
// Structure: tern_pass1 + tern_pass2 (16 blk/tensor), conv12 (4-chunk
// im2col MFMA, stride-36 A, 4 blocks/CU), conv3_mfma (256 blk), fc (1024).
// Cross-session drift ~15% on identical code — compare within-run only.
// Known: harness's ~40us ws-poison fill is inside dur_us (uncontrollable).
// ---------------------------------------------------------------------------

typedef __attribute__((ext_vector_type(8))) short bf16x8;
typedef __attribute__((ext_vector_type(4))) float f32x4;

// ---- ws layout (float offsets) --------------------------------------------
// pb: pabs[5][16] @0, ps1[5][16] @80, pcnt[5][16] @160
static const size_t OFF_PB    = 0;        // 240 f32
static const size_t OFF_W1B   = 256;      // [32][32] bf16 = 512 f32
static const size_t OFF_W2B   = 1056;     // [64][25][32] bf16 = 25600 f32
static const size_t OFF_W3B   = 26656;    // [128][1600] bf16  = 102400 f32
static const size_t OFF_FW1T  = 129056;   // [120][84] f32, +-1/0
static const size_t OFF_FW2T  = 139136;   // [84][10] f32, +-1/0
static const size_t OFF_P2B   = 139976;   // [1024][1600] bf16 = 819200 f32
static const size_t OFF_H3    = 959176;   // [1024][120] f32
// total ~4.3 MB

#define BPT 16   // blocks per tensor in ternarize passes

__device__ __forceinline__ ushort f2bf(float v) {   // RNE float->bf16 bits
    unsigned u = __float_as_uint(v);
    unsigned r = (u + 0x7FFFu + ((u >> 16) & 1u)) >> 16;
    return (ushort)r;
}
__device__ __forceinline__ float bf2f(ushort h) {
    return __uint_as_float((unsigned)h << 16);
}

// tanh via hw exp: 1 - 2e/(1+e), e = exp(-2|x|) in (0,1] -> no overflow.
__device__ __forceinline__ float tanh_fast(float x) {
    float e = __expf(-2.0f * fabsf(x));
    float r = 1.0f - 2.0f * e / (1.0f + e);
    return copysignf(r, x);
}

__device__ __forceinline__ void tensor_select(int tensor,
        const float* w1, const float* w2, const float* w3,
        const float* fw1, const float* fw2,
        const float*& src, int& O, int& K) {
    switch (tensor) {
        case 0: src = w1;  O = 32;  K = 25;   break;
        case 1: src = w2;  O = 64;  K = 800;  break;
        case 2: src = w3;  O = 120; K = 1600; break;
        case 3: src = fw1; O = 84;  K = 120;  break;
        default: src = fw2; O = 10; K = 84;   break;
    }
}

__device__ __forceinline__ float block_sum_256(float v, float* sbuf) {
    #pragma unroll
    for (int off = 32; off > 0; off >>= 1) v += __shfl_down(v, off);
    const int wid = threadIdx.x >> 6;
    if ((threadIdx.x & 63) == 0) sbuf[wid] = v;
    __syncthreads();
    return sbuf[0] + sbuf[1] + sbuf[2] + sbuf[3];
}

// alpha for `tensor` from pass2 partials (redundant per-thread compute)
__device__ __forceinline__ float alpha_of(const float* pb, int tensor) {
    float s1 = 0.f, c = 0.f;
    #pragma unroll
    for (int i = 0; i < BPT; ++i) {
        s1 += pb[80 + tensor * BPT + i];
        c  += pb[160 + tensor * BPT + i];
    }
    return s1 / fmaxf(c, 1.0f);
}

// ---------------------------------------------------------------------------
__global__ __launch_bounds__(256)
void tern_pass1(const float* w1, const float* w2, const float* w3,
                const float* fw1, const float* fw2, float* pb) {
    __shared__ float sbuf[4];
    const int tensor = blockIdx.x / BPT;
    const int blk    = blockIdx.x % BPT;
    const float* src; int O, K;
    tensor_select(tensor, w1, w2, w3, fw1, fw2, src, O, K);
    const int n = O * K;
    float s = 0.f;
    for (int i = blk * 256 + threadIdx.x; i < n; i += BPT * 256)
        s += fabsf(src[i]);
    s = block_sum_256(s, sbuf);
    if (threadIdx.x == 0) pb[tensor * BPT + blk] = s;
}

// pass2: delta from pass1 partials; quantize to +-1/0; write masked partials.
__global__ __launch_bounds__(256)
void tern_pass2(const float* w1, const float* w2, const float* w3,
                const float* fw1, const float* fw2,
                ushort* w1b, ushort* w2b, ushort* w3b,
                float* fw1t, float* fw2t, float* pb) {
    __shared__ float sbuf[4];
    const int tensor = blockIdx.x / BPT;
    const int blk    = blockIdx.x % BPT;
    const float* src; int O, K;
    tensor_select(tensor, w1, w2, w3, fw1, fw2, src, O, K);
    const int n = O * K;
    float tot = 0.f;
    #pragma unroll
    for (int i = 0; i < BPT; ++i) tot += pb[tensor * BPT + i];
    const float delta = 0.7f * tot / (float)n;

    const ushort BP = 0x3F80u, BN = 0xBF80u;   // bf16 +1, -1
    float s1 = 0.f, cnt = 0.f;

    if (tensor == 0) {
        // w1 -> bf16 [oc][32]: k 0..24 = taps, k 25..31 = 0 (pads MFMA K)
        for (int j = blk * 256 + threadIdx.x; j < 1024; j += BPT * 256) {
            const int oc = j >> 5, kk = j & 31;
            ushort qb = 0;
            if (kk < 25) {
                float w = src[oc * 25 + kk];
                float aw = fabsf(w);
                if (aw > delta) { s1 += aw; cnt += 1.f; qb = (w > 0.f) ? BP : BN; }
            }
            w1b[j] = qb;
        }
    } else if (tensor == 2) {
        // w3 -> bf16 [oc][1600] row-linear; zero-fill pad rows 120..127
        for (int i = blk * 256 + threadIdx.x; i < 128 * 1600; i += BPT * 256) {
            ushort qb = 0;
            if (i < n) {
                float w = src[i];
                float aw = fabsf(w);
                if (aw > delta) { s1 += aw; cnt += 1.f; qb = (w > 0.f) ? BP : BN; }
            }
            w3b[i] = qb;
        }
    } else if (tensor == 1) {
        // w2 -> bf16 [oc][tap][ic]; src is [oc][ic][kh][kw]
        for (int i = blk * 256 + threadIdx.x; i < n; i += BPT * 256) {
            float w = src[i];
            float aw = fabsf(w);
            ushort qb = 0;
            if (aw > delta) { s1 += aw; cnt += 1.f; qb = (w > 0.f) ? BP : BN; }
            int oc = i / 800;
            int r  = i - oc * 800;
            int ic = r / 25;
            int tap = r - ic * 25;
            w2b[oc * 800 + tap * 32 + ic] = qb;
        }
    } else {
        float* dst = (tensor == 3) ? fw1t : fw2t;
        for (int i = blk * 256 + threadIdx.x; i < n; i += BPT * 256) {
            float w = src[i];
            float aw = fabsf(w);
            float q = 0.f;
            if (aw > delta) { s1 += aw; cnt += 1.f; q = (w > 0.f) ? 1.f : -1.f; }
            int o = i / K;
            int k = i - o * K;
            dst[k * O + o] = q;      // transpose to [k][O]
        }
    }
    s1 = block_sum_256(s1, sbuf);
    __syncthreads();
    cnt = block_sum_256(cnt, sbuf);
    if (threadIdx.x == 0) {
        pb[80 + tensor * BPT + blk]  = s1;
        pb[160 + tensor * BPT + blk] = cnt;
    }
}

// ---------------------------------------------------------------------------
// conv2 MFMA inner (stride 40 sxt)
template<int TBASE, int TCNT>
__device__ __forceinline__ void conv2_phase(
        const ushort* __restrict__ w2b, const ushort* sxt,
        int n0, int mt0, int lane, f32x4 acc[4][2]) {
    const int col = lane & 15, quad = lane >> 4;
    bf16x8 bfr[TCNT][2];
    #pragma unroll
    for (int i = 0; i < TCNT; ++i) {
        const int tap = TBASE + i;
        #pragma unroll
        for (int np = 0; np < 2; ++np) {
            const int oc = n0 + np * 16 + col;
            bfr[i][np] = *(const bf16x8*)(w2b + (oc * 25 + tap) * 32 + quad * 8);
        }
    }
    #pragma unroll
    for (int mi = 0; mi < 4; ++mi) {
        int m = (mt0 + mi) * 16 + col;
        m = m < 100 ? m : 99;                     // clamp padding rows
        const int oh = m / 10, ow = m - oh * 10;
        const ushort* abase = sxt + (oh * 14 + ow) * 40 + quad * 8;
        #pragma unroll
        for (int i = 0; i < TCNT; ++i) {
            const int tap = TBASE + i;
            const int kh = tap / 5, kw = tap - kh * 5;
            bf16x8 af = *(const bf16x8*)(abase + (kh * 14 + kw) * 40);
            acc[mi][0] = __builtin_amdgcn_mfma_f32_16x16x32_bf16(af, bfr[i][0], acc[mi][0], 0, 0, 0);
            acc[mi][1] = __builtin_amdgcn_mfma_f32_16x16x32_bf16(af, bfr[i][1], acc[mi][1], 0, 0, 0);
        }
    }
}

// ---------------------------------------------------------------------------
// conv12: conv1 MFMA (4-chunk im2col, conflict-free stride-36 A) + pool +
// conv2 MFMA + pool. One image per block, 4 blocks/CU.
__global__ __launch_bounds__(256)
void conv12_kernel(const float* __restrict__ x, const ushort* __restrict__ w1b,
                   const float* __restrict__ b1, const ushort* __restrict__ w2b,
                   const float* __restrict__ b2, const float* __restrict__ pb,
                   ushort* __restrict__ p2b) {
    __shared__ __align__(16) char smem[40776];
    ushort* A      = (ushort*)smem;
    ushort* sxt    = (ushort*)smem;
    ushort* hb1    = (ushort*)(smem + 15680);
    float*  hb2    = (float*) (smem + 15680);
    ushort* sxb    = (ushort*)(smem + 38720);
    float*  salpha = (float*) (smem + 40768);

    const int n = blockIdx.x;
    const int t = threadIdx.x;
    const int wave = t >> 6, lane = t & 63;
    const int col = lane & 15, quad = lane >> 4;

    bf16x8 B0 = *(const bf16x8*)(w1b + col * 32 + quad * 8);
    bf16x8 B1 = *(const bf16x8*)(w1b + (col + 16) * 32 + quad * 8);
    const float b1reg = b1[t & 31];

    {   // stage x -> bf16 sxb
        float4 v = ((const float4*)(x + (size_t)n * 1024))[t];
        ushort4 q;
        q.x = f2bf(v.x); q.y = f2bf(v.y); q.z = f2bf(v.z); q.w = f2bf(v.w);
        *(ushort4*)(sxb + t * 4) = q;
        if (t == 0) salpha[0] = alpha_of(pb, 0);
        if (t == 1) salpha[1] = alpha_of(pb, 1);
    }
    __syncthreads();

    // ---- conv1: 4 chunks of tiles {13,13,13,10} -------------------------
    #pragma unroll
    for (int c = 0; c < 4; ++c) {
        const int tbase = c * 13;
        const int ct    = (c == 3) ? 10 : 13;
        const int pbase = tbase * 16;
        const int rows  = ct * 16;

        for (int r = t; r < rows; r += 256) {
            const int p = pbase + r;
            const int oh = p / 28, ow = p % 28;
            ushort v[25];
            #pragma unroll
            for (int kh = 0; kh < 5; ++kh) {
                const ushort* rr = sxb + (oh + kh) * 32 + ow;
                v[kh*5+0]=rr[0]; v[kh*5+1]=rr[1]; v[kh*5+2]=rr[2];
                v[kh*5+3]=rr[3]; v[kh*5+4]=rr[4];
            }
            uint2* arow = (uint2*)(A + r * 36);   // 72B rows: banks 18r%32
            #pragma unroll
            for (int j = 0; j < 6; ++j) {
                uint2 w;
                w.x = (unsigned)v[4*j]   | ((unsigned)v[4*j+1] << 16);
                w.y = (unsigned)v[4*j+2] | ((unsigned)v[4*j+3] << 16);
                arow[j] = w;
            }
            uint2 w6; w6.x = (unsigned)v[24]; w6.y = 0u;
            arow[6] = w6;
            uint2 w7; w7.x = 0u; w7.y = 0u;
            arow[7] = w7;
        }
        __syncthreads();

        for (int tl = wave; tl < ct; tl += 4) {
            const ushort* ap = A + (tl * 16 + col) * 36 + quad * 8;
            ushort4 lo = *(const ushort4*)ap;
            ushort4 hi = *(const ushort4*)(ap + 4);
            bf16x8 af;
            af[0]=(short)lo.x; af[1]=(short)lo.y; af[2]=(short)lo.z; af[3]=(short)lo.w;
            af[4]=(short)hi.x; af[5]=(short)hi.y; af[6]=(short)hi.z; af[7]=(short)hi.w;
            f32x4 z = {};
            f32x4 c0 = __builtin_amdgcn_mfma_f32_16x16x32_bf16(af, B0, z, 0, 0, 0);
            f32x4 c1 = __builtin_amdgcn_mfma_f32_16x16x32_bf16(af, B1, z, 0, 0, 0);
            const int p = pbase + tl * 16 + quad * 4;
            const int oh = p / 28, ow2 = (p % 28) >> 1;
            const int pos = oh * 14 + ow2;
            hb1[pos * 32 + col]            = f2bf(fmaxf(c0[0], c0[1]));
            hb1[(pos + 1) * 32 + col]      = f2bf(fmaxf(c0[2], c0[3]));
            hb1[pos * 32 + col + 16]       = f2bf(fmaxf(c1[0], c1[1]));
            hb1[(pos + 1) * 32 + col + 16] = f2bf(fmaxf(c1[2], c1[3]));
        }
        __syncthreads();
    }

    // ---- vertical pool + alpha/bias + tanh -> sxt (overlays A) ----------
    {
        const float a1 = salpha[0];
        const int oc = t & 31;
        for (int idx = t; idx < 6272; idx += 256) {
            const int pos2 = idx >> 5;
            const int ph = pos2 / 14, pw = pos2 - ph * 14;
            const int in0 = (2 * ph) * 14 + pw;
            float m = fmaxf(bf2f(hb1[in0 * 32 + oc]),
                            bf2f(hb1[(in0 + 14) * 32 + oc]));
            sxt[pos2 * 40 + oc] = f2bf(tanh_fast(fmaf(a1, m, b1reg)));
        }
    }
    __syncthreads();

    // ---- conv2 MFMA -----------------------------------------------------
    const int n0  = (wave & 1) * 32;
    const int mt0 = (wave >> 1) * 4;
    f32x4 acc2[4][2] = {};
    conv2_phase<0, 13>(w2b, sxt, n0, mt0, lane, acc2);
    conv2_phase<13, 12>(w2b, sxt, n0, mt0, lane, acc2);

    {   // horizontal pool in-register -> hb2[oc][50]
        #pragma unroll
        for (int mi = 0; mi < 4; ++mi) {
            const int mrow = (mt0 + mi) * 16 + quad * 4;
            if (mrow < 100) {
                #pragma unroll
                for (int np = 0; np < 2; ++np) {
                    const int oc = n0 + np * 16 + col;
                    float2 hm;
                    hm.x = fmaxf(acc2[mi][np][0], acc2[mi][np][1]);
                    hm.y = fmaxf(acc2[mi][np][2], acc2[mi][np][3]);
                    *(float2*)(&hb2[oc * 50 + (mrow >> 1)]) = hm;
                }
            }
        }
    }
    __syncthreads();

    const float a2 = salpha[1];
    for (int idx = t; idx < 1600; idx += 256) {
        const int oc = idx / 25, r = idx - oc * 25;
        const int ph = r / 5, pw = r - ph * 5;
        const float* hb = &hb2[oc * 50 + ph * 10 + pw];
        float m = fmaxf(hb[0], hb[5]);
        p2b[(size_t)n * 1600 + idx] = f2bf(tanh_fast(fmaf(a2, m, b2[oc])));
    }
}

// ---------------------------------------------------------------------------
// conv3 as MFMA GEMM: h3[1024][120] = tanh(a3*(P2 x W3^T) + b3)
template<int STEPS>
__device__ __forceinline__ void conv3_chunk(const ushort* Abase, const ushort* B0,
                                            const ushort* B1, f32x4& acc0, f32x4& acc1) {
    #pragma unroll
    for (int s = 0; s < STEPS; ++s) {
        bf16x8 af = *(const bf16x8*)(Abase + s * 32);
        bf16x8 b0 = *(const bf16x8*)(B0 + s * 32);
        bf16x8 b1 = *(const bf16x8*)(B1 + s * 32);
        acc0 = __builtin_amdgcn_mfma_f32_16x16x32_bf16(af, b0, acc0, 0, 0, 0);
        acc1 = __builtin_amdgcn_mfma_f32_16x16x32_bf16(af, b1, acc1, 0, 0, 0);
    }
}

__global__ __launch_bounds__(256)
void conv3_mfma(const ushort* __restrict__ p2b, const ushort* __restrict__ w3b,
                const float* __restrict__ b3, const float* __restrict__ pb,
                float* __restrict__ h3) {
    __shared__ float red[4][64][8];   // [wave][lane][np*4+reg]
    __shared__ float salpha;
    const int t = threadIdx.x;
    const int wave = t >> 6, lane = t & 63;
    const int mt = blockIdx.x >> 2;       // 0..63
    const int npair = blockIdx.x & 3;     // 0..3
    const int col = lane & 15, quad = lane >> 4;
    const int kstart = (wave < 2) ? wave * 13 : 26 + (wave - 2) * 12;  // 0,13,26,38

    if (t == 0) salpha = alpha_of(pb, 2);

    const ushort* Abase = p2b + (size_t)(mt * 16 + col) * 1600 + kstart * 32 + quad * 8;
    const ushort* B0 = w3b + (size_t)(npair * 32 + col) * 1600 + kstart * 32 + quad * 8;
    const ushort* B1 = B0 + 16 * 1600;

    f32x4 acc0 = {}, acc1 = {};
    if (wave < 2) conv3_chunk<13>(Abase, B0, B1, acc0, acc1);
    else          conv3_chunk<12>(Abase, B0, B1, acc0, acc1);

    #pragma unroll
    for (int r = 0; r < 4; ++r) {
        red[wave][lane][r]     = acc0[r];
        red[wave][lane][4 + r] = acc1[r];
    }
    __syncthreads();

    {   // thread t: lane l = t&63, reg vh = t>>6; handles np = 0 and 1
        const float a3 = salpha;
        const int l = t & 63, vh = t >> 6;
        const int lcol = l & 15, lquad = l >> 4;
        const int img = mt * 16 + lquad * 4 + vh;
        #pragma unroll
        for (int j = 0; j < 2; ++j) {
            const int v = j * 4 + vh;
            float s = red[0][l][v] + red[1][l][v] + red[2][l][v] + red[3][l][v];
            const int oc = npair * 32 + j * 16 + lcol;
            if (oc < 120) h3[(size_t)img * 120 + oc] = tanh_fast(fmaf(a3, s, b3[oc]));
        }
    }
}

// ---------------------------------------------------------------------------
// fc1 + tanh + fc2 + softmax. Block per image; alpha folded.
__global__ __launch_bounds__(128)
void fc_kernel(const float* __restrict__ h3, const float* __restrict__ fw1t,
               const float* __restrict__ fb1, const float* __restrict__ fw2t,
               const float* __restrict__ fb2, const float* __restrict__ pb,
               float* __restrict__ out) {
    const int n = blockIdx.x;
    __shared__ float sh[120];
    __shared__ float sh4[84];
    __shared__ float sl[10];
    __shared__ float salpha[2];
    const int t = threadIdx.x;
    if (t < 120) sh[t] = h3[(size_t)n * 120 + t];
    if (t == 120) salpha[0] = alpha_of(pb, 3);
    if (t == 121) salpha[1] = alpha_of(pb, 4);
    __syncthreads();
    if (t < 84) {
        const float af1 = salpha[0];
        float a = 0.f;
        #pragma unroll 4
        for (int k = 0; k < 120; ++k) a = fmaf(fw1t[k * 84 + t], sh[k], a);
        sh4[t] = tanh_fast(fmaf(af1, a, fb1[t]));
    }
    __syncthreads();
    if (t < 10) {
        const float af2 = salpha[1];
        float a = 0.f;
        #pragma unroll 4
        for (int k = 0; k < 84; ++k) a = fmaf(fw2t[k * 10 + t], sh4[k], a);
        const float lg = fmaf(af2, a, fb2[t]);
        sl[t] = lg;
        out[(size_t)n * 10 + t] = lg;
    }
    __syncthreads();
    if (t < 10) {
        float m = -INFINITY;
        #pragma unroll
        for (int i = 0; i < 10; ++i) m = fmaxf(m, sl[i]);
        float s = 0.f;
        #pragma unroll
        for (int i = 0; i < 10; ++i) s += expf(sl[i] - m);
        out[10240 + (size_t)n * 10 + t] = expf(sl[t] - m) / s;
    }
}

// ---------------------------------------------------------------------------
extern "C" void kernel_launch(void* const* d_in, const int* in_sizes, int n_in,
                              void* d_out, int out_size, void* d_ws, size_t ws_size,
                              hipStream_t stream) {
    const float* x   = (const float*)d_in[0];
    const float* w1  = (const float*)d_in[1];
    const float* b1  = (const float*)d_in[2];
    const float* w2  = (const float*)d_in[3];
    const float* b2  = (const float*)d_in[4];
    const float* w3  = (const float*)d_in[5];
    const float* b3  = (const float*)d_in[6];
    const float* fw1 = (const float*)d_in[7];
    const float* fb1 = (const float*)d_in[8];
    const float* fw2 = (const float*)d_in[9];
    const float* fb2 = (const float*)d_in[10];

    float* ws = (float*)d_ws;
    float*  pb   = ws + OFF_PB;
    ushort* w1b  = (ushort*)(ws + OFF_W1B);
    ushort* w2b  = (ushort*)(ws + OFF_W2B);
    ushort* w3b  = (ushort*)(ws + OFF_W3B);
    float*  fw1t = ws + OFF_FW1T;
    float*  fw2t = ws + OFF_FW2T;
    ushort* p2b  = (ushort*)(ws + OFF_P2B);
    float*  h3   = ws + OFF_H3;
    float*  out  = (float*)d_out;

    tern_pass1<<<5 * BPT, 256, 0, stream>>>(w1, w2, w3, fw1, fw2, pb);
    tern_pass2<<<5 * BPT, 256, 0, stream>>>(w1, w2, w3, fw1, fw2,
                                            w1b, w2b, w3b, fw1t, fw2t, pb);
    conv12_kernel<<<1024, 256, 0, stream>>>(x, w1b, b1, w2b, b2, pb, p2b);
    conv3_mfma<<<256, 256, 0, stream>>>(p2b, w3b, b3, pb, h3);
    fc_kernel<<<1024, 128, 0, stream>>>(h3, fw1t, fb1, fw2t, fb2, pb, out);
}

// Round 2
// 154.786 us; speedup vs baseline: 1.0545x; 1.0545x over previous
//
#include <hip/hip_runtime.h>
#include <hip/hip_bf16.h>
#include <math.h>

// ---------------------------------------------------------------------------
// TernaryLeNet5 forward.
// R16: from R15 baseline (163.2us, conv12=44.5us MfmaUtil12/VALU32/Occ21).
//  (1) conv2 tap-outer: B-frag loaded once/tap (VGPR=80 vs 104-reg source
//      proved compiler was re-fetching B per mi). Same acc order: bit-exact.
//  (2) pool1 oc-pair uint vectorization (halve LDS ops + addressing).
//  (3) conv3_mfma 512 blocks x 16-oc (2 waves/SIMD vs 1; same K-split and
//      red-sum order: bit-exact).
// absmax pinned at 0.00390625 -> no f32 reassociation anywhere.
// Structure: tern_pass1 + tern_pass2 (16 blk/tensor), conv12 (4-chunk
// im2col MFMA, stride-36 A, 4 blocks/CU), conv3_mfma (512 blk), fc (1024).
// Known: harness's ~40us ws-poison fill is inside dur_us (uncontrollable).
// ---------------------------------------------------------------------------

typedef __attribute__((ext_vector_type(8))) short bf16x8;
typedef __attribute__((ext_vector_type(4))) float f32x4;

// ---- ws layout (float offsets) --------------------------------------------
// pb: pabs[5][16] @0, ps1[5][16] @80, pcnt[5][16] @160
static const size_t OFF_PB    = 0;        // 240 f32
static const size_t OFF_W1B   = 256;      // [32][32] bf16 = 512 f32
static const size_t OFF_W2B   = 1056;     // [64][25][32] bf16 = 25600 f32
static const size_t OFF_W3B   = 26656;    // [128][1600] bf16  = 102400 f32
static const size_t OFF_FW1T  = 129056;   // [120][84] f32, +-1/0
static const size_t OFF_FW2T  = 139136;   // [84][10] f32, +-1/0
static const size_t OFF_P2B   = 139976;   // [1024][1600] bf16 = 819200 f32
static const size_t OFF_H3    = 959176;   // [1024][120] f32
// total ~4.3 MB

#define BPT 16   // blocks per tensor in ternarize passes

__device__ __forceinline__ ushort f2bf(float v) {   // RNE float->bf16 bits
    unsigned u = __float_as_uint(v);
    unsigned r = (u + 0x7FFFu + ((u >> 16) & 1u)) >> 16;
    return (ushort)r;
}
__device__ __forceinline__ float bf2f(ushort h) {
    return __uint_as_float((unsigned)h << 16);
}

// tanh via hw exp: 1 - 2e/(1+e), e = exp(-2|x|) in (0,1] -> no overflow.
__device__ __forceinline__ float tanh_fast(float x) {
    float e = __expf(-2.0f * fabsf(x));
    float r = 1.0f - 2.0f * e / (1.0f + e);
    return copysignf(r, x);
}

__device__ __forceinline__ void tensor_select(int tensor,
        const float* w1, const float* w2, const float* w3,
        const float* fw1, const float* fw2,
        const float*& src, int& O, int& K) {
    switch (tensor) {
        case 0: src = w1;  O = 32;  K = 25;   break;
        case 1: src = w2;  O = 64;  K = 800;  break;
        case 2: src = w3;  O = 120; K = 1600; break;
        case 3: src = fw1; O = 84;  K = 120;  break;
        default: src = fw2; O = 10; K = 84;   break;
    }
}

__device__ __forceinline__ float block_sum_256(float v, float* sbuf) {
    #pragma unroll
    for (int off = 32; off > 0; off >>= 1) v += __shfl_down(v, off);
    const int wid = threadIdx.x >> 6;
    if ((threadIdx.x & 63) == 0) sbuf[wid] = v;
    __syncthreads();
    return sbuf[0] + sbuf[1] + sbuf[2] + sbuf[3];
}

// alpha for `tensor` from pass2 partials (redundant per-thread compute)
__device__ __forceinline__ float alpha_of(const float* pb, int tensor) {
    float s1 = 0.f, c = 0.f;
    #pragma unroll
    for (int i = 0; i < BPT; ++i) {
        s1 += pb[80 + tensor * BPT + i];
        c  += pb[160 + tensor * BPT + i];
    }
    return s1 / fmaxf(c, 1.0f);
}

// ---------------------------------------------------------------------------
__global__ __launch_bounds__(256)
void tern_pass1(const float* w1, const float* w2, const float* w3,
                const float* fw1, const float* fw2, float* pb) {
    __shared__ float sbuf[4];
    const int tensor = blockIdx.x / BPT;
    const int blk    = blockIdx.x % BPT;
    const float* src; int O, K;
    tensor_select(tensor, w1, w2, w3, fw1, fw2, src, O, K);
    const int n = O * K;
    float s = 0.f;
    for (int i = blk * 256 + threadIdx.x; i < n; i += BPT * 256)
        s += fabsf(src[i]);
    s = block_sum_256(s, sbuf);
    if (threadIdx.x == 0) pb[tensor * BPT + blk] = s;
}

// pass2: delta from pass1 partials; quantize to +-1/0; write masked partials.
__global__ __launch_bounds__(256)
void tern_pass2(const float* w1, const float* w2, const float* w3,
                const float* fw1, const float* fw2,
                ushort* w1b, ushort* w2b, ushort* w3b,
                float* fw1t, float* fw2t, float* pb) {
    __shared__ float sbuf[4];
    const int tensor = blockIdx.x / BPT;
    const int blk    = blockIdx.x % BPT;
    const float* src; int O, K;
    tensor_select(tensor, w1, w2, w3, fw1, fw2, src, O, K);
    const int n = O * K;
    float tot = 0.f;
    #pragma unroll
    for (int i = 0; i < BPT; ++i) tot += pb[tensor * BPT + i];
    const float delta = 0.7f * tot / (float)n;

    const ushort BP = 0x3F80u, BN = 0xBF80u;   // bf16 +1, -1
    float s1 = 0.f, cnt = 0.f;

    if (tensor == 0) {
        // w1 -> bf16 [oc][32]: k 0..24 = taps, k 25..31 = 0 (pads MFMA K)
        for (int j = blk * 256 + threadIdx.x; j < 1024; j += BPT * 256) {
            const int oc = j >> 5, kk = j & 31;
            ushort qb = 0;
            if (kk < 25) {
                float w = src[oc * 25 + kk];
                float aw = fabsf(w);
                if (aw > delta) { s1 += aw; cnt += 1.f; qb = (w > 0.f) ? BP : BN; }
            }
            w1b[j] = qb;
        }
    } else if (tensor == 2) {
        // w3 -> bf16 [oc][1600] row-linear; zero-fill pad rows 120..127
        for (int i = blk * 256 + threadIdx.x; i < 128 * 1600; i += BPT * 256) {
            ushort qb = 0;
            if (i < n) {
                float w = src[i];
                float aw = fabsf(w);
                if (aw > delta) { s1 += aw; cnt += 1.f; qb = (w > 0.f) ? BP : BN; }
            }
            w3b[i] = qb;
        }
    } else if (tensor == 1) {
        // w2 -> bf16 [oc][tap][ic]; src is [oc][ic][kh][kw]
        for (int i = blk * 256 + threadIdx.x; i < n; i += BPT * 256) {
            float w = src[i];
            float aw = fabsf(w);
            ushort qb = 0;
            if (aw > delta) { s1 += aw; cnt += 1.f; qb = (w > 0.f) ? BP : BN; }
            int oc = i / 800;
            int r  = i - oc * 800;
            int ic = r / 25;
            int tap = r - ic * 25;
            w2b[oc * 800 + tap * 32 + ic] = qb;
        }
    } else {
        float* dst = (tensor == 3) ? fw1t : fw2t;
        for (int i = blk * 256 + threadIdx.x; i < n; i += BPT * 256) {
            float w = src[i];
            float aw = fabsf(w);
            float q = 0.f;
            if (aw > delta) { s1 += aw; cnt += 1.f; q = (w > 0.f) ? 1.f : -1.f; }
            int o = i / K;
            int k = i - o * K;
            dst[k * O + o] = q;      // transpose to [k][O]
        }
    }
    s1 = block_sum_256(s1, sbuf);
    __syncthreads();
    cnt = block_sum_256(cnt, sbuf);
    if (threadIdx.x == 0) {
        pb[80 + tensor * BPT + blk]  = s1;
        pb[160 + tensor * BPT + blk] = cnt;
    }
}

// ---------------------------------------------------------------------------
// conv2 MFMA inner, tap-outer: each B-fragment loaded exactly once and
// reused across the 4 mi MFMAs. Per-acc tap order 0..24 preserved (bit-exact
// vs mi-outer version).
__device__ __forceinline__ void conv2_all(
        const ushort* __restrict__ w2b, const ushort* sxt,
        int n0, int mt0, int lane, f32x4 acc[4][2]) {
    const int col = lane & 15, quad = lane >> 4;
    const ushort* abase[4];
    #pragma unroll
    for (int mi = 0; mi < 4; ++mi) {
        int m = (mt0 + mi) * 16 + col;
        m = m < 100 ? m : 99;                     // clamp padding rows
        const int oh = m / 10, ow = m - oh * 10;
        abase[mi] = sxt + (oh * 14 + ow) * 40 + quad * 8;
    }
    const ushort* wb0 = w2b + (size_t)(n0 + col) * 25 * 32 + quad * 8;
    const ushort* wb1 = wb0 + 16 * 25 * 32;
    #pragma unroll
    for (int tap = 0; tap < 25; ++tap) {
        const int kh = tap / 5, kw = tap - kh * 5;
        const int aoff = (kh * 14 + kw) * 40;
        bf16x8 b0 = *(const bf16x8*)(wb0 + tap * 32);
        bf16x8 b1 = *(const bf16x8*)(wb1 + tap * 32);
        #pragma unroll
        for (int mi = 0; mi < 4; ++mi) {
            bf16x8 af = *(const bf16x8*)(abase[mi] + aoff);
            acc[mi][0] = __builtin_amdgcn_mfma_f32_16x16x32_bf16(af, b0, acc[mi][0], 0, 0, 0);
            acc[mi][1] = __builtin_amdgcn_mfma_f32_16x16x32_bf16(af, b1, acc[mi][1], 0, 0, 0);
        }
    }
}

// ---------------------------------------------------------------------------
// conv12: conv1 MFMA (4-chunk im2col, conflict-free stride-36 A) + pool +
// conv2 MFMA + pool. One image per block, 4 blocks/CU.
__global__ __launch_bounds__(256)
void conv12_kernel(const float* __restrict__ x, const ushort* __restrict__ w1b,
                   const float* __restrict__ b1, const ushort* __restrict__ w2b,
                   const float* __restrict__ b2, const float* __restrict__ pb,
                   ushort* __restrict__ p2b) {
    __shared__ __align__(16) char smem[40776];
    ushort* A      = (ushort*)smem;
    ushort* sxt    = (ushort*)smem;
    ushort* hb1    = (ushort*)(smem + 15680);
    float*  hb2    = (float*) (smem + 15680);
    ushort* sxb    = (ushort*)(smem + 38720);
    float*  salpha = (float*) (smem + 40768);

    const int n = blockIdx.x;
    const int t = threadIdx.x;
    const int wave = t >> 6, lane = t & 63;
    const int col = lane & 15, quad = lane >> 4;

    bf16x8 B0 = *(const bf16x8*)(w1b + col * 32 + quad * 8);
    bf16x8 B1 = *(const bf16x8*)(w1b + (col + 16) * 32 + quad * 8);

    {   // stage x -> bf16 sxb
        float4 v = ((const float4*)(x + (size_t)n * 1024))[t];
        ushort4 q;
        q.x = f2bf(v.x); q.y = f2bf(v.y); q.z = f2bf(v.z); q.w = f2bf(v.w);
        *(ushort4*)(sxb + t * 4) = q;
        if (t == 0) salpha[0] = alpha_of(pb, 0);
        if (t == 1) salpha[1] = alpha_of(pb, 1);
    }
    __syncthreads();

    // ---- conv1: 4 chunks of tiles {13,13,13,10} -------------------------
    #pragma unroll
    for (int c = 0; c < 4; ++c) {
        const int tbase = c * 13;
        const int ct    = (c == 3) ? 10 : 13;
        const int pbase = tbase * 16;
        const int rows  = ct * 16;

        for (int r = t; r < rows; r += 256) {
            const int p = pbase + r;
            const int oh = p / 28, ow = p % 28;
            ushort v[25];
            #pragma unroll
            for (int kh = 0; kh < 5; ++kh) {
                const ushort* rr = sxb + (oh + kh) * 32 + ow;
                v[kh*5+0]=rr[0]; v[kh*5+1]=rr[1]; v[kh*5+2]=rr[2];
                v[kh*5+3]=rr[3]; v[kh*5+4]=rr[4];
            }
            uint2* arow = (uint2*)(A + r * 36);   // 72B rows: banks 18r%32
            #pragma unroll
            for (int j = 0; j < 6; ++j) {
                uint2 w;
                w.x = (unsigned)v[4*j]   | ((unsigned)v[4*j+1] << 16);
                w.y = (unsigned)v[4*j+2] | ((unsigned)v[4*j+3] << 16);
                arow[j] = w;
            }
            uint2 w6; w6.x = (unsigned)v[24]; w6.y = 0u;
            arow[6] = w6;
            uint2 w7; w7.x = 0u; w7.y = 0u;
            arow[7] = w7;
        }
        __syncthreads();

        for (int tl = wave; tl < ct; tl += 4) {
            const ushort* ap = A + (tl * 16 + col) * 36 + quad * 8;
            ushort4 lo = *(const ushort4*)ap;
            ushort4 hi = *(const ushort4*)(ap + 4);
            bf16x8 af;
            af[0]=(short)lo.x; af[1]=(short)lo.y; af[2]=(short)lo.z; af[3]=(short)lo.w;
            af[4]=(short)hi.x; af[5]=(short)hi.y; af[6]=(short)hi.z; af[7]=(short)hi.w;
            f32x4 z = {};
            f32x4 c0 = __builtin_amdgcn_mfma_f32_16x16x32_bf16(af, B0, z, 0, 0, 0);
            f32x4 c1 = __builtin_amdgcn_mfma_f32_16x16x32_bf16(af, B1, z, 0, 0, 0);
            const int p = pbase + tl * 16 + quad * 4;
            const int oh = p / 28, ow2 = (p % 28) >> 1;
            const int pos = oh * 14 + ow2;
            hb1[pos * 32 + col]            = f2bf(fmaxf(c0[0], c0[1]));
            hb1[(pos + 1) * 32 + col]      = f2bf(fmaxf(c0[2], c0[3]));
            hb1[pos * 32 + col + 16]       = f2bf(fmaxf(c1[0], c1[1]));
            hb1[(pos + 1) * 32 + col + 16] = f2bf(fmaxf(c1[2], c1[3]));
        }
        __syncthreads();
    }

    // ---- vertical pool + alpha/bias + tanh -> sxt (overlays A) ----------
    // oc-pair vectorized: thread handles ocs (t&15)*2, (t&15)*2+1 via uint
    // LDS ops. Same per-element math/rounding as scalar version.
    {
        const float a1 = salpha[0];
        const int oc2 = (t & 15) * 2;
        const float b1a = b1[oc2], b1b = b1[oc2 + 1];
        for (int idx = t; idx < 3136; idx += 256) {
            const int pos2 = idx >> 4;
            const int ph = pos2 / 14, pw = pos2 - ph * 14;
            const int in0 = (2 * ph) * 14 + pw;
            const uint u0 = *(const uint*)(hb1 + in0 * 32 + oc2);
            const uint u1 = *(const uint*)(hb1 + (in0 + 14) * 32 + oc2);
            const float m0 = fmaxf(bf2f((ushort)u0), bf2f((ushort)u1));
            const float m1 = fmaxf(bf2f((ushort)(u0 >> 16)), bf2f((ushort)(u1 >> 16)));
            const ushort r0 = f2bf(tanh_fast(fmaf(a1, m0, b1a)));
            const ushort r1 = f2bf(tanh_fast(fmaf(a1, m1, b1b)));
            *(uint*)(sxt + pos2 * 40 + oc2) = (uint)r0 | ((uint)r1 << 16);
        }
    }
    __syncthreads();

    // ---- conv2 MFMA -----------------------------------------------------
    const int n0  = (wave & 1) * 32;
    const int mt0 = (wave >> 1) * 4;
    f32x4 acc2[4][2] = {};
    conv2_all(w2b, sxt, n0, mt0, lane, acc2);

    {   // horizontal pool in-register -> hb2[oc][50]
        #pragma unroll
        for (int mi = 0; mi < 4; ++mi) {
            const int mrow = (mt0 + mi) * 16 + quad * 4;
            if (mrow < 100) {
                #pragma unroll
                for (int np = 0; np < 2; ++np) {
                    const int oc = n0 + np * 16 + col;
                    float2 hm;
                    hm.x = fmaxf(acc2[mi][np][0], acc2[mi][np][1]);
                    hm.y = fmaxf(acc2[mi][np][2], acc2[mi][np][3]);
                    *(float2*)(&hb2[oc * 50 + (mrow >> 1)]) = hm;
                }
            }
        }
    }
    __syncthreads();

    const float a2 = salpha[1];
    for (int idx = t; idx < 1600; idx += 256) {
        const int oc = idx / 25, r = idx - oc * 25;
        const int ph = r / 5, pw = r - ph * 5;
        const float* hb = &hb2[oc * 50 + ph * 10 + pw];
        float m = fmaxf(hb[0], hb[5]);
        p2b[(size_t)n * 1600 + idx] = f2bf(tanh_fast(fmaf(a2, m, b2[oc])));
    }
}

// ---------------------------------------------------------------------------
// conv3 as MFMA GEMM: h3[1024][120] = tanh(a3*(P2 x W3^T) + b3)
// 512 blocks x (16 imgs x 16 ocs): 2 waves/SIMD (was 1). Same per-wave
// K-split (13/13/12/12) and red-sum order as the 256-block version:
// bit-exact.
template<int STEPS>
__device__ __forceinline__ void conv3_chunk(const ushort* Abase, const ushort* B0,
                                            f32x4& acc0) {
    #pragma unroll
    for (int s = 0; s < STEPS; ++s) {
        bf16x8 af = *(const bf16x8*)(Abase + s * 32);
        bf16x8 b0 = *(const bf16x8*)(B0 + s * 32);
        acc0 = __builtin_amdgcn_mfma_f32_16x16x32_bf16(af, b0, acc0, 0, 0, 0);
    }
}

__global__ __launch_bounds__(256)
void conv3_mfma(const ushort* __restrict__ p2b, const ushort* __restrict__ w3b,
                const float* __restrict__ b3, const float* __restrict__ pb,
                float* __restrict__ h3) {
    __shared__ float red[4][64][4];   // [wave][lane][reg]
    __shared__ float salpha;
    const int t = threadIdx.x;
    const int wave = t >> 6, lane = t & 63;
    const int mt   = blockIdx.x >> 3;     // 0..63
    const int noct = blockIdx.x & 7;      // 0..7 (16 ocs each)
    const int col = lane & 15, quad = lane >> 4;
    const int kstart = (wave < 2) ? wave * 13 : 26 + (wave - 2) * 12;  // 0,13,26,38

    if (t == 0) salpha = alpha_of(pb, 2);

    const ushort* Abase = p2b + (size_t)(mt * 16 + col) * 1600 + kstart * 32 + quad * 8;
    const ushort* B0 = w3b + (size_t)(noct * 16 + col) * 1600 + kstart * 32 + quad * 8;

    f32x4 acc0 = {};
    if (wave < 2) conv3_chunk<13>(Abase, B0, acc0);
    else          conv3_chunk<12>(Abase, B0, acc0);

    #pragma unroll
    for (int r = 0; r < 4; ++r) red[wave][lane][r] = acc0[r];
    __syncthreads();

    {   // thread t: lane l = t&63, reg vh = t>>6; one (img, oc) each
        const float a3 = salpha;
        const int l = t & 63, vh = t >> 6;
        const int lcol = l & 15, lquad = l >> 4;
        const int img = mt * 16 + lquad * 4 + vh;
        float s = red[0][l][vh] + red[1][l][vh] + red[2][l][vh] + red[3][l][vh];
        const int oc = noct * 16 + lcol;
        if (oc < 120) h3[(size_t)img * 120 + oc] = tanh_fast(fmaf(a3, s, b3[oc]));
    }
}

// ---------------------------------------------------------------------------
// fc1 + tanh + fc2 + softmax. Block per image; alpha folded.
__global__ __launch_bounds__(128)
void fc_kernel(const float* __restrict__ h3, const float* __restrict__ fw1t,
               const float* __restrict__ fb1, const float* __restrict__ fw2t,
               const float* __restrict__ fb2, const float* __restrict__ pb,
               float* __restrict__ out) {
    const int n = blockIdx.x;
    __shared__ float sh[120];
    __shared__ float sh4[84];
    __shared__ float sl[10];
    __shared__ float salpha[2];
    const int t = threadIdx.x;
    if (t < 120) sh[t] = h3[(size_t)n * 120 + t];
    if (t == 120) salpha[0] = alpha_of(pb, 3);
    if (t == 121) salpha[1] = alpha_of(pb, 4);
    __syncthreads();
    if (t < 84) {
        const float af1 = salpha[0];
        float a = 0.f;
        #pragma unroll 4
        for (int k = 0; k < 120; ++k) a = fmaf(fw1t[k * 84 + t], sh[k], a);
        sh4[t] = tanh_fast(fmaf(af1, a, fb1[t]));
    }
    __syncthreads();
    if (t < 10) {
        const float af2 = salpha[1];
        float a = 0.f;
        #pragma unroll 4
        for (int k = 0; k < 84; ++k) a = fmaf(fw2t[k * 10 + t], sh4[k], a);
        const float lg = fmaf(af2, a, fb2[t]);
        sl[t] = lg;
        out[(size_t)n * 10 + t] = lg;
    }
    __syncthreads();
    if (t < 10) {
        float m = -INFINITY;
        #pragma unroll
        for (int i = 0; i < 10; ++i) m = fmaxf(m, sl[i]);
        float s = 0.f;
        #pragma unroll
        for (int i = 0; i < 10; ++i) s += expf(sl[i] - m);
        out[10240 + (size_t)n * 10 + t] = expf(sl[t] - m) / s;
    }
}

// ---------------------------------------------------------------------------
extern "C" void kernel_launch(void* const* d_in, const int* in_sizes, int n_in,
                              void* d_out, int out_size, void* d_ws, size_t ws_size,
                              hipStream_t stream) {
    const float* x   = (const float*)d_in[0];
    const float* w1  = (const float*)d_in[1];
    const float* b1  = (const float*)d_in[2];
    const float* w2  = (const float*)d_in[3];
    const float* b2  = (const float*)d_in[4];
    const float* w3  = (const float*)d_in[5];
    const float* b3  = (const float*)d_in[6];
    const float* fw1 = (const float*)d_in[7];
    const float* fb1 = (const float*)d_in[8];
    const float* fw2 = (const float*)d_in[9];
    const float* fb2 = (const float*)d_in[10];

    float* ws = (float*)d_ws;
    float*  pb   = ws + OFF_PB;
    ushort* w1b  = (ushort*)(ws + OFF_W1B);
    ushort* w2b  = (ushort*)(ws + OFF_W2B);
    ushort* w3b  = (ushort*)(ws + OFF_W3B);
    float*  fw1t = ws + OFF_FW1T;
    float*  fw2t = ws + OFF_FW2T;
    ushort* p2b  = (ushort*)(ws + OFF_P2B);
    float*  h3   = ws + OFF_H3;
    float*  out  = (float*)d_out;

    tern_pass1<<<5 * BPT, 256, 0, stream>>>(w1, w2, w3, fw1, fw2, pb);
    tern_pass2<<<5 * BPT, 256, 0, stream>>>(w1, w2, w3, fw1, fw2,
                                            w1b, w2b, w3b, fw1t, fw2t, pb);
    conv12_kernel<<<1024, 256, 0, stream>>>(x, w1b, b1, w2b, b2, pb, p2b);
    conv3_mfma<<<512, 256, 0, stream>>>(p2b, w3b, b3, pb, h3);
    fc_kernel<<<1024, 128, 0, stream>>>(h3, fw1t, fb1, fw2t, fb2, pb, out);
}

// Round 3
// 153.017 us; speedup vs baseline: 1.0666x; 1.0116x over previous
//
#include <hip/hip_runtime.h>
#include <hip/hip_bf16.h>
#include <math.h>

// ---------------------------------------------------------------------------
// TernaryLeNet5 forward.
// R17: from R16 (154.8us; top-5 all 42us ws-poison fills => conv12 < 42us).
//  (1) conv2 B-loads: explicit depth-4 rolling register prefetch (VGPR=80
//      showed compiler wasn't pipelining; 25x2 L2 loads ~200cyc vs ~90cyc
//      per-tap compute => stalls). __launch_bounds__(256,4) caps VGPR 128
//      (LDS already pins 4 blk/CU). Tap order per acc unchanged: bit-exact.
//  (2) fc1: fw1t staged via LDS in 4x30-k double-buffered float4 chunks;
//      fw2t staged to LDS. Same k order + fmaf chain: bit-exact.
// absmax pinned at 0.00390625 -> no f32 reassociation anywhere.
// Structure: tern_pass1 + tern_pass2 (16 blk/tensor), conv12 (4-chunk
// im2col MFMA, stride-36 A, 4 blocks/CU), conv3_mfma (512 blk), fc (1024).
// Known: harness's ~42us ws-poison fill is inside dur_us (uncontrollable).
// ---------------------------------------------------------------------------

typedef __attribute__((ext_vector_type(8))) short bf16x8;
typedef __attribute__((ext_vector_type(4))) float f32x4;

// ---- ws layout (float offsets) --------------------------------------------
// pb: pabs[5][16] @0, ps1[5][16] @80, pcnt[5][16] @160
static const size_t OFF_PB    = 0;        // 240 f32
static const size_t OFF_W1B   = 256;      // [32][32] bf16 = 512 f32
static const size_t OFF_W2B   = 1056;     // [64][25][32] bf16 = 25600 f32
static const size_t OFF_W3B   = 26656;    // [128][1600] bf16  = 102400 f32
static const size_t OFF_FW1T  = 129056;   // [120][84] f32, +-1/0
static const size_t OFF_FW2T  = 139136;   // [84][10] f32, +-1/0
static const size_t OFF_P2B   = 139976;   // [1024][1600] bf16 = 819200 f32
static const size_t OFF_H3    = 959176;   // [1024][120] f32
// total ~4.3 MB

#define BPT 16   // blocks per tensor in ternarize passes

__device__ __forceinline__ ushort f2bf(float v) {   // RNE float->bf16 bits
    unsigned u = __float_as_uint(v);
    unsigned r = (u + 0x7FFFu + ((u >> 16) & 1u)) >> 16;
    return (ushort)r;
}
__device__ __forceinline__ float bf2f(ushort h) {
    return __uint_as_float((unsigned)h << 16);
}

// tanh via hw exp: 1 - 2e/(1+e), e = exp(-2|x|) in (0,1] -> no overflow.
__device__ __forceinline__ float tanh_fast(float x) {
    float e = __expf(-2.0f * fabsf(x));
    float r = 1.0f - 2.0f * e / (1.0f + e);
    return copysignf(r, x);
}

__device__ __forceinline__ void tensor_select(int tensor,
        const float* w1, const float* w2, const float* w3,
        const float* fw1, const float* fw2,
        const float*& src, int& O, int& K) {
    switch (tensor) {
        case 0: src = w1;  O = 32;  K = 25;   break;
        case 1: src = w2;  O = 64;  K = 800;  break;
        case 2: src = w3;  O = 120; K = 1600; break;
        case 3: src = fw1; O = 84;  K = 120;  break;
        default: src = fw2; O = 10; K = 84;   break;
    }
}

__device__ __forceinline__ float block_sum_256(float v, float* sbuf) {
    #pragma unroll
    for (int off = 32; off > 0; off >>= 1) v += __shfl_down(v, off);
    const int wid = threadIdx.x >> 6;
    if ((threadIdx.x & 63) == 0) sbuf[wid] = v;
    __syncthreads();
    return sbuf[0] + sbuf[1] + sbuf[2] + sbuf[3];
}

// alpha for `tensor` from pass2 partials (redundant per-thread compute)
__device__ __forceinline__ float alpha_of(const float* pb, int tensor) {
    float s1 = 0.f, c = 0.f;
    #pragma unroll
    for (int i = 0; i < BPT; ++i) {
        s1 += pb[80 + tensor * BPT + i];
        c  += pb[160 + tensor * BPT + i];
    }
    return s1 / fmaxf(c, 1.0f);
}

// ---------------------------------------------------------------------------
__global__ __launch_bounds__(256)
void tern_pass1(const float* w1, const float* w2, const float* w3,
                const float* fw1, const float* fw2, float* pb) {
    __shared__ float sbuf[4];
    const int tensor = blockIdx.x / BPT;
    const int blk    = blockIdx.x % BPT;
    const float* src; int O, K;
    tensor_select(tensor, w1, w2, w3, fw1, fw2, src, O, K);
    const int n = O * K;
    float s = 0.f;
    for (int i = blk * 256 + threadIdx.x; i < n; i += BPT * 256)
        s += fabsf(src[i]);
    s = block_sum_256(s, sbuf);
    if (threadIdx.x == 0) pb[tensor * BPT + blk] = s;
}

// pass2: delta from pass1 partials; quantize to +-1/0; write masked partials.
__global__ __launch_bounds__(256)
void tern_pass2(const float* w1, const float* w2, const float* w3,
                const float* fw1, const float* fw2,
                ushort* w1b, ushort* w2b, ushort* w3b,
                float* fw1t, float* fw2t, float* pb) {
    __shared__ float sbuf[4];
    const int tensor = blockIdx.x / BPT;
    const int blk    = blockIdx.x % BPT;
    const float* src; int O, K;
    tensor_select(tensor, w1, w2, w3, fw1, fw2, src, O, K);
    const int n = O * K;
    float tot = 0.f;
    #pragma unroll
    for (int i = 0; i < BPT; ++i) tot += pb[tensor * BPT + i];
    const float delta = 0.7f * tot / (float)n;

    const ushort BP = 0x3F80u, BN = 0xBF80u;   // bf16 +1, -1
    float s1 = 0.f, cnt = 0.f;

    if (tensor == 0) {
        // w1 -> bf16 [oc][32]: k 0..24 = taps, k 25..31 = 0 (pads MFMA K)
        for (int j = blk * 256 + threadIdx.x; j < 1024; j += BPT * 256) {
            const int oc = j >> 5, kk = j & 31;
            ushort qb = 0;
            if (kk < 25) {
                float w = src[oc * 25 + kk];
                float aw = fabsf(w);
                if (aw > delta) { s1 += aw; cnt += 1.f; qb = (w > 0.f) ? BP : BN; }
            }
            w1b[j] = qb;
        }
    } else if (tensor == 2) {
        // w3 -> bf16 [oc][1600] row-linear; zero-fill pad rows 120..127
        for (int i = blk * 256 + threadIdx.x; i < 128 * 1600; i += BPT * 256) {
            ushort qb = 0;
            if (i < n) {
                float w = src[i];
                float aw = fabsf(w);
                if (aw > delta) { s1 += aw; cnt += 1.f; qb = (w > 0.f) ? BP : BN; }
            }
            w3b[i] = qb;
        }
    } else if (tensor == 1) {
        // w2 -> bf16 [oc][tap][ic]; src is [oc][ic][kh][kw]
        for (int i = blk * 256 + threadIdx.x; i < n; i += BPT * 256) {
            float w = src[i];
            float aw = fabsf(w);
            ushort qb = 0;
            if (aw > delta) { s1 += aw; cnt += 1.f; qb = (w > 0.f) ? BP : BN; }
            int oc = i / 800;
            int r  = i - oc * 800;
            int ic = r / 25;
            int tap = r - ic * 25;
            w2b[oc * 800 + tap * 32 + ic] = qb;
        }
    } else {
        float* dst = (tensor == 3) ? fw1t : fw2t;
        for (int i = blk * 256 + threadIdx.x; i < n; i += BPT * 256) {
            float w = src[i];
            float aw = fabsf(w);
            float q = 0.f;
            if (aw > delta) { s1 += aw; cnt += 1.f; q = (w > 0.f) ? 1.f : -1.f; }
            int o = i / K;
            int k = i - o * K;
            dst[k * O + o] = q;      // transpose to [k][O]
        }
    }
    s1 = block_sum_256(s1, sbuf);
    __syncthreads();
    cnt = block_sum_256(cnt, sbuf);
    if (threadIdx.x == 0) {
        pb[80 + tensor * BPT + blk]  = s1;
        pb[160 + tensor * BPT + blk] = cnt;
    }
}

// ---------------------------------------------------------------------------
// conv2 MFMA inner, tap-outer with explicit depth-4 register prefetch of the
// B fragments (w2b, L2-resident). Per-acc tap order 0..24 preserved:
// bit-exact vs non-pipelined version.
#define C2PF 4
__device__ __forceinline__ void conv2_all(
        const ushort* __restrict__ w2b, const ushort* sxt,
        int n0, int mt0, int lane, f32x4 acc[4][2]) {
    const int col = lane & 15, quad = lane >> 4;
    const ushort* abase[4];
    #pragma unroll
    for (int mi = 0; mi < 4; ++mi) {
        int m = (mt0 + mi) * 16 + col;
        m = m < 100 ? m : 99;                     // clamp padding rows
        const int oh = m / 10, ow = m - oh * 10;
        abase[mi] = sxt + (oh * 14 + ow) * 40 + quad * 8;
    }
    const ushort* wb0 = w2b + (size_t)(n0 + col) * 800 + quad * 8;
    const ushort* wb1 = wb0 + 16 * 800;
    bf16x8 pb0[C2PF], pb1[C2PF];
    #pragma unroll
    for (int i = 0; i < C2PF; ++i) {
        pb0[i] = *(const bf16x8*)(wb0 + i * 32);
        pb1[i] = *(const bf16x8*)(wb1 + i * 32);
    }
    #pragma unroll
    for (int tap = 0; tap < 25; ++tap) {
        const int slot = tap & (C2PF - 1);        // static after full unroll
        const bf16x8 b0 = pb0[slot];
        const bf16x8 b1 = pb1[slot];
        if (tap + C2PF < 25) {
            pb0[slot] = *(const bf16x8*)(wb0 + (tap + C2PF) * 32);
            pb1[slot] = *(const bf16x8*)(wb1 + (tap + C2PF) * 32);
        }
        const int kh = tap / 5, kw = tap - kh * 5;
        const int aoff = (kh * 14 + kw) * 40;
        #pragma unroll
        for (int mi = 0; mi < 4; ++mi) {
            bf16x8 af = *(const bf16x8*)(abase[mi] + aoff);
            acc[mi][0] = __builtin_amdgcn_mfma_f32_16x16x32_bf16(af, b0, acc[mi][0], 0, 0, 0);
            acc[mi][1] = __builtin_amdgcn_mfma_f32_16x16x32_bf16(af, b1, acc[mi][1], 0, 0, 0);
        }
    }
}

// ---------------------------------------------------------------------------
// conv12: conv1 MFMA (4-chunk im2col, conflict-free stride-36 A) + pool +
// conv2 MFMA + pool. One image per block, 4 blocks/CU (LDS-pinned), so cap
// VGPR via min-waves=4/EU.
__global__ __launch_bounds__(256, 4)
void conv12_kernel(const float* __restrict__ x, const ushort* __restrict__ w1b,
                   const float* __restrict__ b1, const ushort* __restrict__ w2b,
                   const float* __restrict__ b2, const float* __restrict__ pb,
                   ushort* __restrict__ p2b) {
    __shared__ __align__(16) char smem[40776];
    ushort* A      = (ushort*)smem;
    ushort* sxt    = (ushort*)smem;
    ushort* hb1    = (ushort*)(smem + 15680);
    float*  hb2    = (float*) (smem + 15680);
    ushort* sxb    = (ushort*)(smem + 38720);
    float*  salpha = (float*) (smem + 40768);

    const int n = blockIdx.x;
    const int t = threadIdx.x;
    const int wave = t >> 6, lane = t & 63;
    const int col = lane & 15, quad = lane >> 4;

    bf16x8 B0 = *(const bf16x8*)(w1b + col * 32 + quad * 8);
    bf16x8 B1 = *(const bf16x8*)(w1b + (col + 16) * 32 + quad * 8);

    {   // stage x -> bf16 sxb
        float4 v = ((const float4*)(x + (size_t)n * 1024))[t];
        ushort4 q;
        q.x = f2bf(v.x); q.y = f2bf(v.y); q.z = f2bf(v.z); q.w = f2bf(v.w);
        *(ushort4*)(sxb + t * 4) = q;
        if (t == 0) salpha[0] = alpha_of(pb, 0);
        if (t == 1) salpha[1] = alpha_of(pb, 1);
    }
    __syncthreads();

    // ---- conv1: 4 chunks of tiles {13,13,13,10} -------------------------
    #pragma unroll
    for (int c = 0; c < 4; ++c) {
        const int tbase = c * 13;
        const int ct    = (c == 3) ? 10 : 13;
        const int pbase = tbase * 16;
        const int rows  = ct * 16;

        for (int r = t; r < rows; r += 256) {
            const int p = pbase + r;
            const int oh = p / 28, ow = p % 28;
            ushort v[25];
            #pragma unroll
            for (int kh = 0; kh < 5; ++kh) {
                const ushort* rr = sxb + (oh + kh) * 32 + ow;
                v[kh*5+0]=rr[0]; v[kh*5+1]=rr[1]; v[kh*5+2]=rr[2];
                v[kh*5+3]=rr[3]; v[kh*5+4]=rr[4];
            }
            uint2* arow = (uint2*)(A + r * 36);   // 72B rows: banks 18r%32
            #pragma unroll
            for (int j = 0; j < 6; ++j) {
                uint2 w;
                w.x = (unsigned)v[4*j]   | ((unsigned)v[4*j+1] << 16);
                w.y = (unsigned)v[4*j+2] | ((unsigned)v[4*j+3] << 16);
                arow[j] = w;
            }
            uint2 w6; w6.x = (unsigned)v[24]; w6.y = 0u;
            arow[6] = w6;
            uint2 w7; w7.x = 0u; w7.y = 0u;
            arow[7] = w7;
        }
        __syncthreads();

        for (int tl = wave; tl < ct; tl += 4) {
            const ushort* ap = A + (tl * 16 + col) * 36 + quad * 8;
            ushort4 lo = *(const ushort4*)ap;
            ushort4 hi = *(const ushort4*)(ap + 4);
            bf16x8 af;
            af[0]=(short)lo.x; af[1]=(short)lo.y; af[2]=(short)lo.z; af[3]=(short)lo.w;
            af[4]=(short)hi.x; af[5]=(short)hi.y; af[6]=(short)hi.z; af[7]=(short)hi.w;
            f32x4 z = {};
            f32x4 c0 = __builtin_amdgcn_mfma_f32_16x16x32_bf16(af, B0, z, 0, 0, 0);
            f32x4 c1 = __builtin_amdgcn_mfma_f32_16x16x32_bf16(af, B1, z, 0, 0, 0);
            const int p = pbase + tl * 16 + quad * 4;
            const int oh = p / 28, ow2 = (p % 28) >> 1;
            const int pos = oh * 14 + ow2;
            hb1[pos * 32 + col]            = f2bf(fmaxf(c0[0], c0[1]));
            hb1[(pos + 1) * 32 + col]      = f2bf(fmaxf(c0[2], c0[3]));
            hb1[pos * 32 + col + 16]       = f2bf(fmaxf(c1[0], c1[1]));
            hb1[(pos + 1) * 32 + col + 16] = f2bf(fmaxf(c1[2], c1[3]));
        }
        __syncthreads();
    }

    // ---- vertical pool + alpha/bias + tanh -> sxt (overlays A) ----------
    // oc-pair vectorized: thread handles ocs (t&15)*2, (t&15)*2+1 via uint
    // LDS ops. Same per-element math/rounding as scalar version.
    {
        const float a1 = salpha[0];
        const int oc2 = (t & 15) * 2;
        const float b1a = b1[oc2], b1b = b1[oc2 + 1];
        for (int idx = t; idx < 3136; idx += 256) {
            const int pos2 = idx >> 4;
            const int ph = pos2 / 14, pw = pos2 - ph * 14;
            const int in0 = (2 * ph) * 14 + pw;
            const uint u0 = *(const uint*)(hb1 + in0 * 32 + oc2);
            const uint u1 = *(const uint*)(hb1 + (in0 + 14) * 32 + oc2);
            const float m0 = fmaxf(bf2f((ushort)u0), bf2f((ushort)u1));
            const float m1 = fmaxf(bf2f((ushort)(u0 >> 16)), bf2f((ushort)(u1 >> 16)));
            const ushort r0 = f2bf(tanh_fast(fmaf(a1, m0, b1a)));
            const ushort r1 = f2bf(tanh_fast(fmaf(a1, m1, b1b)));
            *(uint*)(sxt + pos2 * 40 + oc2) = (uint)r0 | ((uint)r1 << 16);
        }
    }
    __syncthreads();

    // ---- conv2 MFMA -----------------------------------------------------
    const int n0  = (wave & 1) * 32;
    const int mt0 = (wave >> 1) * 4;
    f32x4 acc2[4][2] = {};
    conv2_all(w2b, sxt, n0, mt0, lane, acc2);

    {   // horizontal pool in-register -> hb2[oc][50]
        #pragma unroll
        for (int mi = 0; mi < 4; ++mi) {
            const int mrow = (mt0 + mi) * 16 + quad * 4;
            if (mrow < 100) {
                #pragma unroll
                for (int np = 0; np < 2; ++np) {
                    const int oc = n0 + np * 16 + col;
                    float2 hm;
                    hm.x = fmaxf(acc2[mi][np][0], acc2[mi][np][1]);
                    hm.y = fmaxf(acc2[mi][np][2], acc2[mi][np][3]);
                    *(float2*)(&hb2[oc * 50 + (mrow >> 1)]) = hm;
                }
            }
        }
    }
    __syncthreads();

    const float a2 = salpha[1];
    for (int idx = t; idx < 1600; idx += 256) {
        const int oc = idx / 25, r = idx - oc * 25;
        const int ph = r / 5, pw = r - ph * 5;
        const float* hb = &hb2[oc * 50 + ph * 10 + pw];
        float m = fmaxf(hb[0], hb[5]);
        p2b[(size_t)n * 1600 + idx] = f2bf(tanh_fast(fmaf(a2, m, b2[oc])));
    }
}

// ---------------------------------------------------------------------------
// conv3 as MFMA GEMM: h3[1024][120] = tanh(a3*(P2 x W3^T) + b3)
// 512 blocks x (16 imgs x 16 ocs): 2 waves/SIMD. Same per-wave K-split
// (13/13/12/12) and red-sum order: bit-exact.
template<int STEPS>
__device__ __forceinline__ void conv3_chunk(const ushort* Abase, const ushort* B0,
                                            f32x4& acc0) {
    #pragma unroll
    for (int s = 0; s < STEPS; ++s) {
        bf16x8 af = *(const bf16x8*)(Abase + s * 32);
        bf16x8 b0 = *(const bf16x8*)(B0 + s * 32);
        acc0 = __builtin_amdgcn_mfma_f32_16x16x32_bf16(af, b0, acc0, 0, 0, 0);
    }
}

__global__ __launch_bounds__(256)
void conv3_mfma(const ushort* __restrict__ p2b, const ushort* __restrict__ w3b,
                const float* __restrict__ b3, const float* __restrict__ pb,
                float* __restrict__ h3) {
    __shared__ float red[4][64][4];   // [wave][lane][reg]
    __shared__ float salpha;
    const int t = threadIdx.x;
    const int wave = t >> 6, lane = t & 63;
    const int mt   = blockIdx.x >> 3;     // 0..63
    const int noct = blockIdx.x & 7;      // 0..7 (16 ocs each)
    const int col = lane & 15, quad = lane >> 4;
    const int kstart = (wave < 2) ? wave * 13 : 26 + (wave - 2) * 12;  // 0,13,26,38

    if (t == 0) salpha = alpha_of(pb, 2);

    const ushort* Abase = p2b + (size_t)(mt * 16 + col) * 1600 + kstart * 32 + quad * 8;
    const ushort* B0 = w3b + (size_t)(noct * 16 + col) * 1600 + kstart * 32 + quad * 8;

    f32x4 acc0 = {};
    if (wave < 2) conv3_chunk<13>(Abase, B0, acc0);
    else          conv3_chunk<12>(Abase, B0, acc0);

    #pragma unroll
    for (int r = 0; r < 4; ++r) red[wave][lane][r] = acc0[r];
    __syncthreads();

    {   // thread t: lane l = t&63, reg vh = t>>6; one (img, oc) each
        const float a3 = salpha;
        const int l = t & 63, vh = t >> 6;
        const int lcol = l & 15, lquad = l >> 4;
        const int img = mt * 16 + lquad * 4 + vh;
        float s = red[0][l][vh] + red[1][l][vh] + red[2][l][vh] + red[3][l][vh];
        const int oc = noct * 16 + lcol;
        if (oc < 120) h3[(size_t)img * 120 + oc] = tanh_fast(fmaf(a3, s, b3[oc]));
    }
}

// ---------------------------------------------------------------------------
// fc1 + tanh + fc2 + softmax. Block per image; alpha folded.
// fw1t streamed through LDS in 4x30-k double-buffered float4 chunks (all 128
// threads stage, compute overlaps next stage); fw2t staged once. Same k
// order and fmaf chain as the global-read version: bit-exact.
__global__ __launch_bounds__(128)
void fc_kernel(const float* __restrict__ h3, const float* __restrict__ fw1t,
               const float* __restrict__ fb1, const float* __restrict__ fw2t,
               const float* __restrict__ fb2, const float* __restrict__ pb,
               float* __restrict__ out) {
    const int n = blockIdx.x;
    __shared__ float sh[120];
    __shared__ float sh4[84];
    __shared__ float sl[10];
    __shared__ float salpha[2];
    __shared__ __align__(16) float wbuf[2][30 * 84];   // 2 x 10,080 B
    __shared__ __align__(16) float fw2s[84 * 10];      // 3,360 B
    const int t = threadIdx.x;
    if (t < 120) sh[t] = h3[(size_t)n * 120 + t];
    if (t == 120) salpha[0] = alpha_of(pb, 3);
    if (t == 121) salpha[1] = alpha_of(pb, 4);
    // stage fw2t (210 float4) + fw1t chunk 0 (630 float4)
    #pragma unroll
    for (int i = 0; i < 2; ++i) {
        const int j = t + i * 128;
        if (j < 210) ((float4*)fw2s)[j] = ((const float4*)fw2t)[j];
    }
    for (int i = t; i < 630; i += 128)
        ((float4*)wbuf[0])[i] = ((const float4*)fw1t)[i];
    __syncthreads();

    float a = 0.f;
    #pragma unroll
    for (int c = 0; c < 4; ++c) {
        if (c < 3) {   // stage chunk c+1 while computing chunk c
            const float4* src = (const float4*)(fw1t + (c + 1) * 2520);
            float4* dst = (float4*)wbuf[(c + 1) & 1];
            for (int i = t; i < 630; i += 128) dst[i] = src[i];
        }
        if (t < 84) {
            const float* wc = wbuf[c & 1];
            #pragma unroll 6
            for (int kk = 0; kk < 30; ++kk)
                a = fmaf(wc[kk * 84 + t], sh[30 * c + kk], a);
        }
        __syncthreads();
    }
    if (t < 84) sh4[t] = tanh_fast(fmaf(salpha[0], a, fb1[t]));
    __syncthreads();
    if (t < 10) {
        const float af2 = salpha[1];
        float a2 = 0.f;
        #pragma unroll 4
        for (int k = 0; k < 84; ++k) a2 = fmaf(fw2s[k * 10 + t], sh4[k], a2);
        const float lg = fmaf(af2, a2, fb2[t]);
        sl[t] = lg;
        out[(size_t)n * 10 + t] = lg;
    }
    __syncthreads();
    if (t < 10) {
        float m = -INFINITY;
        #pragma unroll
        for (int i = 0; i < 10; ++i) m = fmaxf(m, sl[i]);
        float s = 0.f;
        #pragma unroll
        for (int i = 0; i < 10; ++i) s += expf(sl[i] - m);
        out[10240 + (size_t)n * 10 + t] = expf(sl[t] - m) / s;
    }
}

// ---------------------------------------------------------------------------
extern "C" void kernel_launch(void* const* d_in, const int* in_sizes, int n_in,
                              void* d_out, int out_size, void* d_ws, size_t ws_size,
                              hipStream_t stream) {
    const float* x   = (const float*)d_in[0];
    const float* w1  = (const float*)d_in[1];
    const float* b1  = (const float*)d_in[2];
    const float* w2  = (const float*)d_in[3];
    const float* b2  = (const float*)d_in[4];
    const float* w3  = (const float*)d_in[5];
    const float* b3  = (const float*)d_in[6];
    const float* fw1 = (const float*)d_in[7];
    const float* fb1 = (const float*)d_in[8];
    const float* fw2 = (const float*)d_in[9];
    const float* fb2 = (const float*)d_in[10];

    float* ws = (float*)d_ws;
    float*  pb   = ws + OFF_PB;
    ushort* w1b  = (ushort*)(ws + OFF_W1B);
    ushort* w2b  = (ushort*)(ws + OFF_W2B);
    ushort* w3b  = (ushort*)(ws + OFF_W3B);
    float*  fw1t = ws + OFF_FW1T;
    float*  fw2t = ws + OFF_FW2T;
    ushort* p2b  = (ushort*)(ws + OFF_P2B);
    float*  h3   = ws + OFF_H3;
    float*  out  = (float*)d_out;

    tern_pass1<<<5 * BPT, 256, 0, stream>>>(w1, w2, w3, fw1, fw2, pb);
    tern_pass2<<<5 * BPT, 256, 0, stream>>>(w1, w2, w3, fw1, fw2,
                                            w1b, w2b, w3b, fw1t, fw2t, pb);
    conv12_kernel<<<1024, 256, 0, stream>>>(x, w1b, b1, w2b, b2, pb, p2b);
    conv3_mfma<<<512, 256, 0, stream>>>(p2b, w3b, b3, pb, h3);
    fc_kernel<<<1024, 128, 0, stream>>>(h3, fw1t, fb1, fw2t, fb2, pb, out);
}

// Round 4
// 148.917 us; speedup vs baseline: 1.0960x; 1.0275x over previous
//
#include <hip/hip_runtime.h>
#include <hip/hip_bf16.h>
#include <math.h>

// ---------------------------------------------------------------------------
// TernaryLeNet5 forward.
// R18: from R17 (153.0us). conv12 conv1 rewrite: Z-ordered im2col rows
// (2x2 pool blocks) so the full 2x2 maxpool + alpha/bias/tanh happens in
// the MFMA epilogue (c0[0..3] = one pool window per quad). Eliminates the
// hb1 LDS buffer (25KB), the pool1 phase, and 3 barriers (9->6; 3 chunks
// {17,16,16} instead of 4). Bit-exact: h-pool maxima pass through bf16
// rounding before the v-max, exactly like the old hb1 path (f2bf monotone,
// same order). conv2/conv3/fc/tern unchanged from R17 to isolate.
// absmax pinned at 0.00390625 -> no f32 reassociation anywhere.
// Known: harness's ~42us ws-poison fill is inside dur_us (uncontrollable);
// top-5 counters show only fills => all our kernels < 42us.
// ---------------------------------------------------------------------------

typedef __attribute__((ext_vector_type(8))) short bf16x8;
typedef __attribute__((ext_vector_type(4))) float f32x4;

// ---- ws layout (float offsets) --------------------------------------------
// pb: pabs[5][16] @0, ps1[5][16] @80, pcnt[5][16] @160
static const size_t OFF_PB    = 0;        // 240 f32
static const size_t OFF_W1B   = 256;      // [32][32] bf16 = 512 f32
static const size_t OFF_W2B   = 1056;     // [64][25][32] bf16 = 25600 f32
static const size_t OFF_W3B   = 26656;    // [128][1600] bf16  = 102400 f32
static const size_t OFF_FW1T  = 129056;   // [120][84] f32, +-1/0
static const size_t OFF_FW2T  = 139136;   // [84][10] f32, +-1/0
static const size_t OFF_P2B   = 139976;   // [1024][1600] bf16 = 819200 f32
static const size_t OFF_H3    = 959176;   // [1024][120] f32
// total ~4.3 MB

#define BPT 16   // blocks per tensor in ternarize passes

__device__ __forceinline__ ushort f2bf(float v) {   // RNE float->bf16 bits
    unsigned u = __float_as_uint(v);
    unsigned r = (u + 0x7FFFu + ((u >> 16) & 1u)) >> 16;
    return (ushort)r;
}
__device__ __forceinline__ float bf2f(ushort h) {
    return __uint_as_float((unsigned)h << 16);
}

// tanh via hw exp: 1 - 2e/(1+e), e = exp(-2|x|) in (0,1] -> no overflow.
__device__ __forceinline__ float tanh_fast(float x) {
    float e = __expf(-2.0f * fabsf(x));
    float r = 1.0f - 2.0f * e / (1.0f + e);
    return copysignf(r, x);
}

__device__ __forceinline__ void tensor_select(int tensor,
        const float* w1, const float* w2, const float* w3,
        const float* fw1, const float* fw2,
        const float*& src, int& O, int& K) {
    switch (tensor) {
        case 0: src = w1;  O = 32;  K = 25;   break;
        case 1: src = w2;  O = 64;  K = 800;  break;
        case 2: src = w3;  O = 120; K = 1600; break;
        case 3: src = fw1; O = 84;  K = 120;  break;
        default: src = fw2; O = 10; K = 84;   break;
    }
}

__device__ __forceinline__ float block_sum_256(float v, float* sbuf) {
    #pragma unroll
    for (int off = 32; off > 0; off >>= 1) v += __shfl_down(v, off);
    const int wid = threadIdx.x >> 6;
    if ((threadIdx.x & 63) == 0) sbuf[wid] = v;
    __syncthreads();
    return sbuf[0] + sbuf[1] + sbuf[2] + sbuf[3];
}

// alpha for `tensor` from pass2 partials (redundant per-thread compute)
__device__ __forceinline__ float alpha_of(const float* pb, int tensor) {
    float s1 = 0.f, c = 0.f;
    #pragma unroll
    for (int i = 0; i < BPT; ++i) {
        s1 += pb[80 + tensor * BPT + i];
        c  += pb[160 + tensor * BPT + i];
    }
    return s1 / fmaxf(c, 1.0f);
}

// ---------------------------------------------------------------------------
__global__ __launch_bounds__(256)
void tern_pass1(const float* w1, const float* w2, const float* w3,
                const float* fw1, const float* fw2, float* pb) {
    __shared__ float sbuf[4];
    const int tensor = blockIdx.x / BPT;
    const int blk    = blockIdx.x % BPT;
    const float* src; int O, K;
    tensor_select(tensor, w1, w2, w3, fw1, fw2, src, O, K);
    const int n = O * K;
    float s = 0.f;
    for (int i = blk * 256 + threadIdx.x; i < n; i += BPT * 256)
        s += fabsf(src[i]);
    s = block_sum_256(s, sbuf);
    if (threadIdx.x == 0) pb[tensor * BPT + blk] = s;
}

// pass2: delta from pass1 partials; quantize to +-1/0; write masked partials.
__global__ __launch_bounds__(256)
void tern_pass2(const float* w1, const float* w2, const float* w3,
                const float* fw1, const float* fw2,
                ushort* w1b, ushort* w2b, ushort* w3b,
                float* fw1t, float* fw2t, float* pb) {
    __shared__ float sbuf[4];
    const int tensor = blockIdx.x / BPT;
    const int blk    = blockIdx.x % BPT;
    const float* src; int O, K;
    tensor_select(tensor, w1, w2, w3, fw1, fw2, src, O, K);
    const int n = O * K;
    float tot = 0.f;
    #pragma unroll
    for (int i = 0; i < BPT; ++i) tot += pb[tensor * BPT + i];
    const float delta = 0.7f * tot / (float)n;

    const ushort BP = 0x3F80u, BN = 0xBF80u;   // bf16 +1, -1
    float s1 = 0.f, cnt = 0.f;

    if (tensor == 0) {
        // w1 -> bf16 [oc][32]: k 0..24 = taps, k 25..31 = 0 (pads MFMA K)
        for (int j = blk * 256 + threadIdx.x; j < 1024; j += BPT * 256) {
            const int oc = j >> 5, kk = j & 31;
            ushort qb = 0;
            if (kk < 25) {
                float w = src[oc * 25 + kk];
                float aw = fabsf(w);
                if (aw > delta) { s1 += aw; cnt += 1.f; qb = (w > 0.f) ? BP : BN; }
            }
            w1b[j] = qb;
        }
    } else if (tensor == 2) {
        // w3 -> bf16 [oc][1600] row-linear; zero-fill pad rows 120..127
        for (int i = blk * 256 + threadIdx.x; i < 128 * 1600; i += BPT * 256) {
            ushort qb = 0;
            if (i < n) {
                float w = src[i];
                float aw = fabsf(w);
                if (aw > delta) { s1 += aw; cnt += 1.f; qb = (w > 0.f) ? BP : BN; }
            }
            w3b[i] = qb;
        }
    } else if (tensor == 1) {
        // w2 -> bf16 [oc][tap][ic]; src is [oc][ic][kh][kw]
        for (int i = blk * 256 + threadIdx.x; i < n; i += BPT * 256) {
            float w = src[i];
            float aw = fabsf(w);
            ushort qb = 0;
            if (aw > delta) { s1 += aw; cnt += 1.f; qb = (w > 0.f) ? BP : BN; }
            int oc = i / 800;
            int r  = i - oc * 800;
            int ic = r / 25;
            int tap = r - ic * 25;
            w2b[oc * 800 + tap * 32 + ic] = qb;
        }
    } else {
        float* dst = (tensor == 3) ? fw1t : fw2t;
        for (int i = blk * 256 + threadIdx.x; i < n; i += BPT * 256) {
            float w = src[i];
            float aw = fabsf(w);
            float q = 0.f;
            if (aw > delta) { s1 += aw; cnt += 1.f; q = (w > 0.f) ? 1.f : -1.f; }
            int o = i / K;
            int k = i - o * K;
            dst[k * O + o] = q;      // transpose to [k][O]
        }
    }
    s1 = block_sum_256(s1, sbuf);
    __syncthreads();
    cnt = block_sum_256(cnt, sbuf);
    if (threadIdx.x == 0) {
        pb[80 + tensor * BPT + blk]  = s1;
        pb[160 + tensor * BPT + blk] = cnt;
    }
}

// ---------------------------------------------------------------------------
// conv2 MFMA inner, tap-outer with explicit depth-4 register prefetch of the
// B fragments (w2b, L2-resident). Per-acc tap order 0..24 preserved:
// bit-exact vs non-pipelined version.
#define C2PF 4
__device__ __forceinline__ void conv2_all(
        const ushort* __restrict__ w2b, const ushort* sxt,
        int n0, int mt0, int lane, f32x4 acc[4][2]) {
    const int col = lane & 15, quad = lane >> 4;
    const ushort* abase[4];
    #pragma unroll
    for (int mi = 0; mi < 4; ++mi) {
        int m = (mt0 + mi) * 16 + col;
        m = m < 100 ? m : 99;                     // clamp padding rows
        const int oh = m / 10, ow = m - oh * 10;
        abase[mi] = sxt + (oh * 14 + ow) * 40 + quad * 8;
    }
    const ushort* wb0 = w2b + (size_t)(n0 + col) * 800 + quad * 8;
    const ushort* wb1 = wb0 + 16 * 800;
    bf16x8 pb0[C2PF], pb1[C2PF];
    #pragma unroll
    for (int i = 0; i < C2PF; ++i) {
        pb0[i] = *(const bf16x8*)(wb0 + i * 32);
        pb1[i] = *(const bf16x8*)(wb1 + i * 32);
    }
    #pragma unroll
    for (int tap = 0; tap < 25; ++tap) {
        const int slot = tap & (C2PF - 1);        // static after full unroll
        const bf16x8 b0 = pb0[slot];
        const bf16x8 b1 = pb1[slot];
        if (tap + C2PF < 25) {
            pb0[slot] = *(const bf16x8*)(wb0 + (tap + C2PF) * 32);
            pb1[slot] = *(const bf16x8*)(wb1 + (tap + C2PF) * 32);
        }
        const int kh = tap / 5, kw = tap - kh * 5;
        const int aoff = (kh * 14 + kw) * 40;
        #pragma unroll
        for (int mi = 0; mi < 4; ++mi) {
            bf16x8 af = *(const bf16x8*)(abase[mi] + aoff);
            acc[mi][0] = __builtin_amdgcn_mfma_f32_16x16x32_bf16(af, b0, acc[mi][0], 0, 0, 0);
            acc[mi][1] = __builtin_amdgcn_mfma_f32_16x16x32_bf16(af, b1, acc[mi][1], 0, 0, 0);
        }
    }
}

// ---------------------------------------------------------------------------
// conv12: conv1 MFMA (Z-ordered im2col: A row p = poolblk*4 + sub,
// sub = (oh&1)*2+(ow&1); 3 chunks {17,16,16}, stride-36 A) with the full
// 2x2 pool + alpha/bias/tanh fused into the MFMA epilogue, then conv2 MFMA
// + h/v pool. One image per block, 4 blocks/CU (LDS-pinned).
// LDS: A @0 (19584B, overlaid by hb2 12800B after conv1), sxt @19584
// (15680B), sxb @35264 (2048B), salpha @37312.
__global__ __launch_bounds__(256, 4)
void conv12_kernel(const float* __restrict__ x, const ushort* __restrict__ w1b,
                   const float* __restrict__ b1, const ushort* __restrict__ w2b,
                   const float* __restrict__ b2, const float* __restrict__ pb,
                   ushort* __restrict__ p2b) {
    __shared__ __align__(16) char smem[37328];
    ushort* A      = (ushort*)smem;
    float*  hb2    = (float*) smem;                   // overlays A (post-conv1)
    ushort* sxt    = (ushort*)(smem + 19584);
    ushort* sxb    = (ushort*)(smem + 35264);
    float*  salpha = (float*) (smem + 37312);

    const int n = blockIdx.x;
    const int t = threadIdx.x;
    const int wave = t >> 6, lane = t & 63;
    const int col = lane & 15, quad = lane >> 4;

    bf16x8 B0 = *(const bf16x8*)(w1b + col * 32 + quad * 8);
    bf16x8 B1 = *(const bf16x8*)(w1b + (col + 16) * 32 + quad * 8);
    const float b1a = b1[col];
    const float b1b = b1[col + 16];

    {   // stage x -> bf16 sxb
        float4 v = ((const float4*)(x + (size_t)n * 1024))[t];
        ushort4 q;
        q.x = f2bf(v.x); q.y = f2bf(v.y); q.z = f2bf(v.z); q.w = f2bf(v.w);
        *(ushort4*)(sxb + t * 4) = q;
        if (t == 0) salpha[0] = alpha_of(pb, 0);
        if (t == 1) salpha[1] = alpha_of(pb, 1);
    }
    __syncthreads();

    // ---- conv1: 3 chunks of tiles {17,16,16}, Z-ordered rows ------------
    const float a1 = salpha[0];
    for (int c = 0; c < 3; ++c) {
        const int tbase = (c == 0) ? 0 : (17 + 16 * (c - 1));   // 0,17,33
        const int ct    = (c == 0) ? 17 : 16;
        const int pbase = tbase * 16;
        const int rows  = ct * 16;

        for (int r = t; r < rows; r += 256) {
            const int p   = pbase + r;
            const int pb4 = p >> 2, sub = p & 3;
            const int oh = 2 * (pb4 / 14) + (sub >> 1);
            const int ow = 2 * (pb4 % 14) + (sub & 1);
            ushort v[25];
            #pragma unroll
            for (int kh = 0; kh < 5; ++kh) {
                const ushort* rr = sxb + (oh + kh) * 32 + ow;
                v[kh*5+0]=rr[0]; v[kh*5+1]=rr[1]; v[kh*5+2]=rr[2];
                v[kh*5+3]=rr[3]; v[kh*5+4]=rr[4];
            }
            uint2* arow = (uint2*)(A + r * 36);   // 72B rows: banks 18r%32
            #pragma unroll
            for (int j = 0; j < 6; ++j) {
                uint2 w;
                w.x = (unsigned)v[4*j]   | ((unsigned)v[4*j+1] << 16);
                w.y = (unsigned)v[4*j+2] | ((unsigned)v[4*j+3] << 16);
                arow[j] = w;
            }
            uint2 w6; w6.x = (unsigned)v[24]; w6.y = 0u;
            arow[6] = w6;
            uint2 w7; w7.x = 0u; w7.y = 0u;
            arow[7] = w7;
        }
        __syncthreads();

        for (int tl = wave; tl < ct; tl += 4) {
            const ushort* ap = A + (tl * 16 + col) * 36 + quad * 8;
            ushort4 lo = *(const ushort4*)ap;
            ushort4 hi = *(const ushort4*)(ap + 4);
            bf16x8 af;
            af[0]=(short)lo.x; af[1]=(short)lo.y; af[2]=(short)lo.z; af[3]=(short)lo.w;
            af[4]=(short)hi.x; af[5]=(short)hi.y; af[6]=(short)hi.z; af[7]=(short)hi.w;
            f32x4 z = {};
            f32x4 c0 = __builtin_amdgcn_mfma_f32_16x16x32_bf16(af, B0, z, 0, 0, 0);
            f32x4 c1 = __builtin_amdgcn_mfma_f32_16x16x32_bf16(af, B1, z, 0, 0, 0);
            // quad's 4 C-rows = one 2x2 pool window (subs 0..3).
            // bf16-round the two h-pool maxima first: bit-exact vs the old
            // hb1 round-trip, then v-max, then alpha/bias/tanh.
            const int pos2 = (pbase >> 2) + tl * 4 + quad;
            const float h01 = bf2f(f2bf(fmaxf(c0[0], c0[1])));
            const float h23 = bf2f(f2bf(fmaxf(c0[2], c0[3])));
            sxt[pos2 * 40 + col] =
                f2bf(tanh_fast(fmaf(a1, fmaxf(h01, h23), b1a)));
            const float g01 = bf2f(f2bf(fmaxf(c1[0], c1[1])));
            const float g23 = bf2f(f2bf(fmaxf(c1[2], c1[3])));
            sxt[pos2 * 40 + col + 16] =
                f2bf(tanh_fast(fmaf(a1, fmaxf(g01, g23), b1b)));
        }
        __syncthreads();
    }

    // ---- conv2 MFMA -----------------------------------------------------
    const int n0  = (wave & 1) * 32;
    const int mt0 = (wave >> 1) * 4;
    f32x4 acc2[4][2] = {};
    conv2_all(w2b, sxt, n0, mt0, lane, acc2);

    {   // horizontal pool in-register -> hb2[oc][50] (overlays dead A)
        #pragma unroll
        for (int mi = 0; mi < 4; ++mi) {
            const int mrow = (mt0 + mi) * 16 + quad * 4;
            if (mrow < 100) {
                #pragma unroll
                for (int np = 0; np < 2; ++np) {
                    const int oc = n0 + np * 16 + col;
                    float2 hm;
                    hm.x = fmaxf(acc2[mi][np][0], acc2[mi][np][1]);
                    hm.y = fmaxf(acc2[mi][np][2], acc2[mi][np][3]);
                    *(float2*)(&hb2[oc * 50 + (mrow >> 1)]) = hm;
                }
            }
        }
    }
    __syncthreads();

    const float a2 = salpha[1];
    for (int idx = t; idx < 1600; idx += 256) {
        const int oc = idx / 25, r = idx - oc * 25;
        const int ph = r / 5, pw = r - ph * 5;
        const float* hb = &hb2[oc * 50 + ph * 10 + pw];
        float m = fmaxf(hb[0], hb[5]);
        p2b[(size_t)n * 1600 + idx] = f2bf(tanh_fast(fmaf(a2, m, b2[oc])));
    }
}

// ---------------------------------------------------------------------------
// conv3 as MFMA GEMM: h3[1024][120] = tanh(a3*(P2 x W3^T) + b3)
// 512 blocks x (16 imgs x 16 ocs): 2 waves/SIMD. Same per-wave K-split
// (13/13/12/12) and red-sum order: bit-exact.
template<int STEPS>
__device__ __forceinline__ void conv3_chunk(const ushort* Abase, const ushort* B0,
                                            f32x4& acc0) {
    #pragma unroll
    for (int s = 0; s < STEPS; ++s) {
        bf16x8 af = *(const bf16x8*)(Abase + s * 32);
        bf16x8 b0 = *(const bf16x8*)(B0 + s * 32);
        acc0 = __builtin_amdgcn_mfma_f32_16x16x32_bf16(af, b0, acc0, 0, 0, 0);
    }
}

__global__ __launch_bounds__(256)
void conv3_mfma(const ushort* __restrict__ p2b, const ushort* __restrict__ w3b,
                const float* __restrict__ b3, const float* __restrict__ pb,
                float* __restrict__ h3) {
    __shared__ float red[4][64][4];   // [wave][lane][reg]
    __shared__ float salpha;
    const int t = threadIdx.x;
    const int wave = t >> 6, lane = t & 63;
    const int mt   = blockIdx.x >> 3;     // 0..63
    const int noct = blockIdx.x & 7;      // 0..7 (16 ocs each)
    const int col = lane & 15, quad = lane >> 4;
    const int kstart = (wave < 2) ? wave * 13 : 26 + (wave - 2) * 12;  // 0,13,26,38

    if (t == 0) salpha = alpha_of(pb, 2);

    const ushort* Abase = p2b + (size_t)(mt * 16 + col) * 1600 + kstart * 32 + quad * 8;
    const ushort* B0 = w3b + (size_t)(noct * 16 + col) * 1600 + kstart * 32 + quad * 8;

    f32x4 acc0 = {};
    if (wave < 2) conv3_chunk<13>(Abase, B0, acc0);
    else          conv3_chunk<12>(Abase, B0, acc0);

    #pragma unroll
    for (int r = 0; r < 4; ++r) red[wave][lane][r] = acc0[r];
    __syncthreads();

    {   // thread t: lane l = t&63, reg vh = t>>6; one (img, oc) each
        const float a3 = salpha;
        const int l = t & 63, vh = t >> 6;
        const int lcol = l & 15, lquad = l >> 4;
        const int img = mt * 16 + lquad * 4 + vh;
        float s = red[0][l][vh] + red[1][l][vh] + red[2][l][vh] + red[3][l][vh];
        const int oc = noct * 16 + lcol;
        if (oc < 120) h3[(size_t)img * 120 + oc] = tanh_fast(fmaf(a3, s, b3[oc]));
    }
}

// ---------------------------------------------------------------------------
// fc1 + tanh + fc2 + softmax. Block per image; alpha folded.
// fw1t streamed through LDS in 4x30-k double-buffered float4 chunks (all 128
// threads stage, compute overlaps next stage); fw2t staged once. Same k
// order and fmaf chain as the global-read version: bit-exact.
__global__ __launch_bounds__(128)
void fc_kernel(const float* __restrict__ h3, const float* __restrict__ fw1t,
               const float* __restrict__ fb1, const float* __restrict__ fw2t,
               const float* __restrict__ fb2, const float* __restrict__ pb,
               float* __restrict__ out) {
    const int n = blockIdx.x;
    __shared__ float sh[120];
    __shared__ float sh4[84];
    __shared__ float sl[10];
    __shared__ float salpha[2];
    __shared__ __align__(16) float wbuf[2][30 * 84];   // 2 x 10,080 B
    __shared__ __align__(16) float fw2s[84 * 10];      // 3,360 B
    const int t = threadIdx.x;
    if (t < 120) sh[t] = h3[(size_t)n * 120 + t];
    if (t == 120) salpha[0] = alpha_of(pb, 3);
    if (t == 121) salpha[1] = alpha_of(pb, 4);
    // stage fw2t (210 float4) + fw1t chunk 0 (630 float4)
    #pragma unroll
    for (int i = 0; i < 2; ++i) {
        const int j = t + i * 128;
        if (j < 210) ((float4*)fw2s)[j] = ((const float4*)fw2t)[j];
    }
    for (int i = t; i < 630; i += 128)
        ((float4*)wbuf[0])[i] = ((const float4*)fw1t)[i];
    __syncthreads();

    float a = 0.f;
    #pragma unroll
    for (int c = 0; c < 4; ++c) {
        if (c < 3) {   // stage chunk c+1 while computing chunk c
            const float4* src = (const float4*)(fw1t + (c + 1) * 2520);
            float4* dst = (float4*)wbuf[(c + 1) & 1];
            for (int i = t; i < 630; i += 128) dst[i] = src[i];
        }
        if (t < 84) {
            const float* wc = wbuf[c & 1];
            #pragma unroll 6
            for (int kk = 0; kk < 30; ++kk)
                a = fmaf(wc[kk * 84 + t], sh[30 * c + kk], a);
        }
        __syncthreads();
    }
    if (t < 84) sh4[t] = tanh_fast(fmaf(salpha[0], a, fb1[t]));
    __syncthreads();
    if (t < 10) {
        const float af2 = salpha[1];
        float a2 = 0.f;
        #pragma unroll 4
        for (int k = 0; k < 84; ++k) a2 = fmaf(fw2s[k * 10 + t], sh4[k], a2);
        const float lg = fmaf(af2, a2, fb2[t]);
        sl[t] = lg;
        out[(size_t)n * 10 + t] = lg;
    }
    __syncthreads();
    if (t < 10) {
        float m = -INFINITY;
        #pragma unroll
        for (int i = 0; i < 10; ++i) m = fmaxf(m, sl[i]);
        float s = 0.f;
        #pragma unroll
        for (int i = 0; i < 10; ++i) s += expf(sl[i] - m);
        out[10240 + (size_t)n * 10 + t] = expf(sl[t] - m) / s;
    }
}

// ---------------------------------------------------------------------------
extern "C" void kernel_launch(void* const* d_in, const int* in_sizes, int n_in,
                              void* d_out, int out_size, void* d_ws, size_t ws_size,
                              hipStream_t stream) {
    const float* x   = (const float*)d_in[0];
    const float* w1  = (const float*)d_in[1];
    const float* b1  = (const float*)d_in[2];
    const float* w2  = (const float*)d_in[3];
    const float* b2  = (const float*)d_in[4];
    const float* w3  = (const float*)d_in[5];
    const float* b3  = (const float*)d_in[6];
    const float* fw1 = (const float*)d_in[7];
    const float* fb1 = (const float*)d_in[8];
    const float* fw2 = (const float*)d_in[9];
    const float* fb2 = (const float*)d_in[10];

    float* ws = (float*)d_ws;
    float*  pb   = ws + OFF_PB;
    ushort* w1b  = (ushort*)(ws + OFF_W1B);
    ushort* w2b  = (ushort*)(ws + OFF_W2B);
    ushort* w3b  = (ushort*)(ws + OFF_W3B);
    float*  fw1t = ws + OFF_FW1T;
    float*  fw2t = ws + OFF_FW2T;
    ushort* p2b  = (ushort*)(ws + OFF_P2B);
    float*  h3   = ws + OFF_H3;
    float*  out  = (float*)d_out;

    tern_pass1<<<5 * BPT, 256, 0, stream>>>(w1, w2, w3, fw1, fw2, pb);
    tern_pass2<<<5 * BPT, 256, 0, stream>>>(w1, w2, w3, fw1, fw2,
                                            w1b, w2b, w3b, fw1t, fw2t, pb);
    conv12_kernel<<<1024, 256, 0, stream>>>(x, w1b, b1, w2b, b2, pb, p2b);
    conv3_mfma<<<512, 256, 0, stream>>>(p2b, w3b, b3, pb, h3);
    fc_kernel<<<1024, 128, 0, stream>>>(h3, fw1t, fb1, fw2t, fb2, pb, out);
}